// Round 15
// baseline (198.303 us; speedup 1.0000x reference)
//
#include <hip/hip_runtime.h>

// ---------------------------------------------------------------------------
// MultiHeadAttentionBlock: q=x@Wq; k=y@Wk; v=y@Wv; attn; +x; LN1; FF+ReLU+res;
// LN2.  B=8 N=1024 D=1024 H=16 DH=64.  All heavy math in bf16 MFMA.
// ---------------------------------------------------------------------------

#define Bb 8
#define Nn 1024
#define Dd 1024
#define Hh 16
#define DH 64
#define Mrows (Bb * 1024)   // 8192

// exp(S/32) == exp2(S * log2(e)/32); fold into Q projection epilogue.
#define QSCL 0.045084220027780106f

typedef float f32x4 __attribute__((ext_vector_type(4)));
typedef __bf16 bf16x8 __attribute__((ext_vector_type(8)));
typedef unsigned int u32x4 __attribute__((ext_vector_type(4)));

#define MFMA16(acc, a, b) \
  acc = __builtin_amdgcn_mfma_f32_16x16x32_bf16((a), (b), (acc), 0, 0, 0)

__device__ __forceinline__ bf16x8 ld_frag(const void* p) {
  u32x4 v = *(const u32x4*)p;
  return __builtin_bit_cast(bf16x8, v);
}

// async global->LDS, 16B per lane (wave-uniform LDS base; per-lane global src)
__device__ __forceinline__ void gload16(const void* g, void* l) {
  __builtin_amdgcn_global_load_lds(
      (const __attribute__((address_space(1))) unsigned int*)g,
      (__attribute__((address_space(3))) unsigned int*)l, 16, 0, 0);
}

__device__ __forceinline__ unsigned short f2bf(float f) {
  return __builtin_bit_cast(unsigned short, (__bf16)f);
}
__device__ __forceinline__ float bf2f(unsigned short s) {
  unsigned int u = ((unsigned int)s) << 16;
  return __builtin_bit_cast(float, u);
}
// pack 2 f32 -> 2 bf16 in one u32 (lo=a, hi=b); no builtin on gfx950
__device__ __forceinline__ unsigned cvt_pk_bf16(float a, float b) {
  unsigned r;
  asm("v_cvt_pk_bf16_f32 %0, %1, %2" : "=v"(r) : "v"(a), "v"(b));
  return r;
}

// ---------------------------------------------------------------------------
// Fused prep: z=0 cvt x->xb, z=1 cvt y->yb, z=2..5 transpose W[z-2] -> Wt bf16
// ---------------------------------------------------------------------------
__global__ __launch_bounds__(256) void prep(
    const float* __restrict__ x, const float* __restrict__ y,
    unsigned short* __restrict__ xb, unsigned short* __restrict__ yb,
    const float* __restrict__ W0, const float* __restrict__ W1,
    const float* __restrict__ W2, const float* __restrict__ W3,
    unsigned short* __restrict__ T0, unsigned short* __restrict__ T1,
    unsigned short* __restrict__ T2, unsigned short* __restrict__ T3) {
  __shared__ float tile[32][33];
  const int z = blockIdx.z, t = threadIdx.x;
  if (z < 2) {
    const float* in = z ? y : x;
    unsigned short* out = z ? yb : xb;
    const int n4 = (Mrows * Dd) / 4;
    int i = blockIdx.x * 256 + t;
    int stride = 1024 * 256;
    for (; i < n4; i += stride) {
      float4 v = ((const float4*)in)[i];
      ushort4 o;
      o.x = f2bf(v.x); o.y = f2bf(v.y); o.z = f2bf(v.z); o.w = f2bf(v.w);
      ((ushort4*)out)[i] = o;
    }
  } else {
    const float* W = z == 2 ? W0 : z == 3 ? W1 : z == 4 ? W2 : W3;
    unsigned short* Wt = z == 2 ? T0 : z == 3 ? T1 : z == 4 ? T2 : T3;
    const int tx = t & 31, ty = t >> 5;
    const int n0 = (blockIdx.x & 31) * 32, k0 = (blockIdx.x >> 5) * 32;
#pragma unroll
    for (int i = ty; i < 32; i += 8)
      tile[i][tx] = W[(size_t)(k0 + i) * Dd + n0 + tx];
    __syncthreads();
#pragma unroll
    for (int i = ty; i < 32; i += 8)
      Wt[(size_t)(n0 + i) * Dd + k0 + tx] = f2bf(tile[tx][i]);
  }
}

// ---------------------------------------------------------------------------
// PIPELINED 2-phase 128x128 GEMM core (T3 "minimum 2-phase" recipe):
//   prologue: STAGE(buf0, t=0); drain; barrier
//   loop t:   STAGE(buf[t+1 & 1], t+1)   <- loads fly over this tile's compute
//             compute from buf[t & 1]     (ds_read + 32 MFMA)
//             __syncthreads()             (vmcnt(0)+lgkmcnt(0) drain + barrier)
// ONE barrier per K-step (was 2) and the load latency is hidden under compute
// instead of stalling all waves at a just-issued drain.
// Hazards: RAW (stage@t -> read@t+1) and WAR (read@t -> restage@t+1) both
// cross the iter-t barrier.  LDS 64 KB (2 buf x {A 16K + B 16K}) -> 2 blk/CU.
// BK=64, XCD-swizzled grid (8, M/128).
// ---------------------------------------------------------------------------
struct GemmCtx { int m0, n0, wm, wn, lr, lk, lg, l, w; };

template <typename EpiFn>
__device__ __forceinline__ void gemm_core(
    const unsigned short* __restrict__ A, const unsigned short* __restrict__ Bt,
    int K, EpiFn epi) {
  __shared__ __attribute__((aligned(16))) unsigned short As[2][2][128 * 32];
  __shared__ __attribute__((aligned(16))) unsigned short Bs[2][2][128 * 32];
  const int bid = blockIdx.y * 8 + blockIdx.x;
  const int nwg = (gridDim.x * gridDim.y);
  const int swz = (bid & 7) * (nwg >> 3) + (bid >> 3);
  const int m0 = (swz >> 3) * 128, n0 = (swz & 7) * 128;
  const int t = threadIdx.x, w = t >> 6, l = t & 63;
  const int wm = (w >> 1) * 64, wn = (w & 1) * 64;
  const int lr = l & 15, lk = (l >> 4) * 8;
  const int rA = t >> 2, sA = (t & 3) * 8;
  const int wb = (w * 64) * 16;

  auto stage = [&](int d, int k0) {
#pragma unroll
    for (int h = 0; h < 2; ++h) {
      const int ko = k0 + h * 32;
      char* ab = (char*)&As[d][h][0];
      char* bb = (char*)&Bs[d][h][0];
      gload16(A + (size_t)(m0 + rA) * K + ko + sA, ab + wb);
      gload16(A + (size_t)(m0 + 64 + rA) * K + ko + sA, ab + wb + 4096);
      gload16(Bt + (size_t)(n0 + rA) * K + ko + sA, bb + wb);
      gload16(Bt + (size_t)(n0 + 64 + rA) * K + ko + sA, bb + wb + 4096);
    }
  };

  f32x4 acc[4][4] = {};

  stage(0, 0);
  __syncthreads();   // compiler drains vmcnt(0) before s_barrier

  const int nt = K >> 6;
#pragma unroll 1
  for (int tt = 0; tt < nt; ++tt) {
    if (tt + 1 < nt) stage((tt + 1) & 1, (tt + 1) * 64);  // issue-early
    const int d = tt & 1;
#pragma unroll
    for (int h = 0; h < 2; ++h) {
      bf16x8 af[4], bfr[4];
#pragma unroll
      for (int i = 0; i < 4; ++i)
        af[i] = ld_frag(&As[d][h][(wm + i * 16 + lr) * 32 + lk]);
#pragma unroll
      for (int j = 0; j < 4; ++j)
        bfr[j] = ld_frag(&Bs[d][h][(wn + j * 16 + lr) * 32 + lk]);
#pragma unroll
      for (int i = 0; i < 4; ++i)
#pragma unroll
        for (int j = 0; j < 4; ++j) MFMA16(acc[i][j], af[i], bfr[j]);
    }
    __syncthreads();  // single drain+barrier per K-step (loads had compute to land)
  }
  GemmCtx c{m0, n0, wm, wn, lr, lk, l >> 4, l, w};
  epi(acc, c);
}

// ---------------------------------------------------------------------------
// Fused Q/K/V projection GEMMs: blockIdx.z selects {Q, K, V}.
//   z=0: Qb = bf16((x@Wq + bq) * QSCL)
//   z=1: Kb = bf16(y@Wk + bk)
//   z=2: Vtb[b][d][c(n)] = bf16(y@Wv + bv)^T with column permute
//        c(n) = (n&~31)|(((n>>2)&3)<<3)|(((n>>4)&1)<<2)|(n&3)  so attn's
//        pi-ordered V A-frags are contiguous b128 reads.
// ---------------------------------------------------------------------------
__global__ __launch_bounds__(256) void gemm_qkv(
    const unsigned short* __restrict__ xb, const unsigned short* __restrict__ yb,
    const unsigned short* __restrict__ WqT, const unsigned short* __restrict__ WkT,
    const unsigned short* __restrict__ WvT,
    const float* __restrict__ bq, const float* __restrict__ bk,
    const float* __restrict__ bv,
    unsigned short* __restrict__ Qb, unsigned short* __restrict__ Kb,
    unsigned short* __restrict__ Vtb) {
  const int z = blockIdx.z;
  const unsigned short* A = (z == 0) ? xb : yb;
  const unsigned short* Bt = (z == 0) ? WqT : (z == 1) ? WkT : WvT;
  const float* bias = (z == 0) ? bq : (z == 1) ? bk : bv;
  unsigned short* Cb = (z == 0) ? Qb : Kb;

  gemm_core(A, Bt, Dd, [&](f32x4 (&acc)[4][4], GemmCtx c) {
#pragma unroll
    for (int i = 0; i < 4; ++i)
#pragma unroll
      for (int j = 0; j < 4; ++j) {
        int col = c.n0 + c.wn + j * 16 + c.lr;
        float bcol = bias[col];
        if (z == 2) {
          int brow = c.m0 + c.wm + i * 16 + c.lg * 4;
          int bi = brow >> 10, nloc = brow & 1023;
          int nperm = (nloc & ~31) | (((nloc >> 2) & 3) << 3) |
                      (((nloc >> 4) & 1) << 2);
          ushort4 o4;
          o4.x = f2bf(acc[i][j][0] + bcol);
          o4.y = f2bf(acc[i][j][1] + bcol);
          o4.z = f2bf(acc[i][j][2] + bcol);
          o4.w = f2bf(acc[i][j][3] + bcol);
          *(ushort4*)(Vtb + ((size_t)bi * Dd + col) * Nn + nperm) = o4;
        } else {
          float scl = (z == 0) ? QSCL : 1.0f;
#pragma unroll
          for (int r = 0; r < 4; ++r) {
            int row = c.m0 + c.wm + i * 16 + c.lg * 4 + r;
            Cb[(size_t)row * Dd + col] = f2bf((acc[i][j][r] + bcol) * scl);
          }
        }
      }
  });
}

// ---------------------------------------------------------------------------
// FF GEMM: Cb = bf16( bf2f(Tres) + relu(acc + bias) )
// ---------------------------------------------------------------------------
__global__ __launch_bounds__(256) void gemm_ff(
    const unsigned short* __restrict__ A, const unsigned short* __restrict__ Bt,
    const float* __restrict__ bias, const unsigned short* __restrict__ Tres,
    unsigned short* __restrict__ Cb) {
  gemm_core(A, Bt, Dd, [&](f32x4 (&acc)[4][4], GemmCtx c) {
#pragma unroll
    for (int i = 0; i < 4; ++i)
#pragma unroll
      for (int j = 0; j < 4; ++j) {
        int col = c.n0 + c.wn + j * 16 + c.lr;
        float bcol = bias[col];
#pragma unroll
        for (int r = 0; r < 4; ++r) {
          int row = c.m0 + c.wm + i * 16 + c.lg * 4 + r;
          size_t idx = (size_t)row * Dd + col;
          Cb[idx] = f2bf(bf2f(Tres[idx]) + fmaxf(acc[i][j][r] + bcol, 0.f));
        }
      }
  });
}

// ---------------------------------------------------------------------------
// Flash attention (R10 best-measured config): 1 block = 8 waves = 256 q-rows
// of one (b,h); 32 q-rows/wave; kv tiles of 64; swapped QK^T; in-register P
// via cvt_pk; ones-MFMA row sums; XOR-swizzled dbuf K/V LDS, ONE barrier/tile.
// ---------------------------------------------------------------------------
__global__ __launch_bounds__(512) void attn_fwd(
    const unsigned short* __restrict__ Qg, const unsigned short* __restrict__ Kg,
    const unsigned short* __restrict__ Vt, unsigned short* __restrict__ Obf) {
  __shared__ __attribute__((aligned(16))) unsigned short KVs[2][2][64 * 64];
  char* lbase = (char*)KVs;   // [buf]{K(8KB) | V(8KB)}

  const int bid = blockIdx.y * 4 + blockIdx.x;   // grid (4,128) = 512 wgs
  const int swz = (bid & 7) * 64 + (bid >> 3);
  const int q0 = (swz & 3) * 256;
  const int by = swz >> 2;
  const int b = by >> 4, h = by & 15;

  const int t = threadIdx.x, w = t >> 6, l = t & 63;
  const int lr = l & 15, lg = l >> 4;

  bf16x8 aq[2][2];
#pragma unroll
  for (int i = 0; i < 2; ++i) {
    const unsigned short* qp =
        Qg + ((size_t)b * Nn + q0 + w * 32 + i * 16 + lr) * Dd + h * DH + lg * 8;
    aq[i][0] = *(const bf16x8*)qp;
    aq[i][1] = *(const bf16x8*)(qp + 32);
  }

  u32x4 one4 = {0x3F803F80u, 0x3F803F80u, 0x3F803F80u, 0x3F803F80u};
  const bf16x8 vones = __builtin_bit_cast(bf16x8, one4);

  const size_t baseK = (size_t)b * Nn * Dd + h * DH;
  const size_t baseV = ((size_t)b * Dd + h * DH) * Nn;

  const int srow = t >> 3, sch = t & 7;
  const int sby = srow * 128 + ((sch * 16) ^ ((srow & 7) << 4));

  uint4 kA = *(const uint4*)(Kg + baseK + (size_t)srow * Dd + sch * 8);
  uint4 vA = *(const uint4*)(Vt + baseV + (size_t)srow * Nn + sch * 8);

  *(uint4*)(lbase + sby) = kA;
  *(uint4*)(lbase + 8192 + sby) = vA;
  __syncthreads();

  f32x4 oacc[4][2] = {};
  f32x4 lacc[2] = {};

  for (int kv = 0; kv < Nn / 64; ++kv) {
    char* kcur = lbase + (kv & 1) * 16384;
    char* vcur = kcur + 8192;
    const bool more = (kv + 1) < Nn / 64;
    if (more) {
      int kvo = (kv + 1) * 64;
      kA = *(const uint4*)(Kg + baseK + (size_t)(kvo + srow) * Dd + sch * 8);
      vA = *(const uint4*)(Vt + baseV + (size_t)srow * Nn + kvo + sch * 8);
    }

    f32x4 st[2][4];
    __builtin_amdgcn_s_setprio(1);
#pragma unroll
    for (int j = 0; j < 4; ++j) {
      const int kro = (j * 16 + lr) * 128;
      bf16x8 k0 = ld_frag(kcur + kro + (((lg ^ (lr & 7))) << 4));
      bf16x8 k1 = ld_frag(kcur + kro + ((((lg + 4) ^ (lr & 7))) << 4));
#pragma unroll
      for (int i = 0; i < 2; ++i) {
        f32x4 zz = {0.f, 0.f, 0.f, 0.f};
        MFMA16(zz, k0, aq[i][0]);
        MFMA16(zz, k1, aq[i][1]);
        st[i][j] = zz;
      }
    }
    __builtin_amdgcn_s_setprio(0);

#pragma unroll
    for (int i = 0; i < 2; ++i)
#pragma unroll
      for (int j = 0; j < 4; ++j) {
        st[i][j][0] = exp2f(st[i][j][0]);
        st[i][j][1] = exp2f(st[i][j][1]);
        st[i][j][2] = exp2f(st[i][j][2]);
        st[i][j][3] = exp2f(st[i][j][3]);
      }

#pragma unroll
    for (int m = 0; m < 2; ++m) {
      bf16x8 pb[2];
#pragma unroll
      for (int i = 0; i < 2; ++i) {
        u32x4 pk;
        pk[0] = cvt_pk_bf16(st[i][2 * m][0], st[i][2 * m][1]);
        pk[1] = cvt_pk_bf16(st[i][2 * m][2], st[i][2 * m][3]);
        pk[2] = cvt_pk_bf16(st[i][2 * m + 1][0], st[i][2 * m + 1][1]);
        pk[3] = cvt_pk_bf16(st[i][2 * m + 1][2], st[i][2 * m + 1][3]);
        pb[i] = __builtin_bit_cast(bf16x8, pk);
      }
      __builtin_amdgcn_s_setprio(1);
      MFMA16(lacc[0], vones, pb[0]);
      MFMA16(lacc[1], vones, pb[1]);
#pragma unroll
      for (int da = 0; da < 4; ++da) {
        const int vrow = da * 16 + lr;
        bf16x8 va = ld_frag(
            vcur + vrow * 128 + (((lg + 4 * m) ^ (vrow & 7)) << 4));
        MFMA16(oacc[da][0], va, pb[0]);
        MFMA16(oacc[da][1], va, pb[1]);
      }
      __builtin_amdgcn_s_setprio(0);
    }

    if (more) {
      char* knxt = lbase + ((kv + 1) & 1) * 16384;
      *(uint4*)(knxt + sby) = kA;
      *(uint4*)(knxt + 8192 + sby) = vA;
      __syncthreads();
    }
  }

#pragma unroll
  for (int i = 0; i < 2; ++i) {
    float rd = 1.f / lacc[i][0];
    const size_t orow = (size_t)b * Nn + q0 + w * 32 + i * 16 + lr;
#pragma unroll
    for (int da = 0; da < 4; ++da) {
      ushort4 o4;
      o4.x = f2bf(oacc[da][i][0] * rd);
      o4.y = f2bf(oacc[da][i][1] * rd);
      o4.z = f2bf(oacc[da][i][2] * rd);
      o4.w = f2bf(oacc[da][i][3] * rd);
      *(ushort4*)(Obf + orow * Dd + h * DH + da * 16 + lg * 4) = o4;
    }
  }
}

// ---------------------------------------------------------------------------
// LayerNorm over D=1024, one block (256 thr) per row.  Inputs bf16.
//   MODE 0: t = LN(X + Oin) -> bf16 out_bf
//   MODE 1: out_f = LN(X)   -> f32
// ---------------------------------------------------------------------------
template <int MODE>
__global__ __launch_bounds__(256) void ln_k(
    const unsigned short* __restrict__ X, const unsigned short* __restrict__ Oin,
    const float* __restrict__ gamma, const float* __restrict__ beta,
    unsigned short* __restrict__ out_bf, float* __restrict__ out_f) {
  __shared__ float red[8];
  const int row = blockIdx.x, t = threadIdx.x;
  ushort4 xu = ((const ushort4*)(X + (size_t)row * Dd))[t];
  float4 v = {bf2f(xu.x), bf2f(xu.y), bf2f(xu.z), bf2f(xu.w)};
  if (MODE == 0) {
    ushort4 o = ((const ushort4*)(Oin + (size_t)row * Dd))[t];
    v.x += bf2f(o.x); v.y += bf2f(o.y); v.z += bf2f(o.z); v.w += bf2f(o.w);
  }
  float s = v.x + v.y + v.z + v.w;
#pragma unroll
  for (int o = 32; o > 0; o >>= 1) s += __shfl_xor(s, o, 64);
  if ((t & 63) == 0) red[t >> 6] = s;
  __syncthreads();
  float mean = (red[0] + red[1] + red[2] + red[3]) * (1.f / 1024.f);
  float dx = v.x - mean, dy = v.y - mean, dz = v.z - mean, dw = v.w - mean;
  float s2 = dx * dx + dy * dy + dz * dz + dw * dw;
#pragma unroll
  for (int o = 32; o > 0; o >>= 1) s2 += __shfl_xor(s2, o, 64);
  if ((t & 63) == 0) red[4 + (t >> 6)] = s2;
  __syncthreads();
  float var = (red[4] + red[5] + red[6] + red[7]) * (1.f / 1024.f);
  float rstd = rsqrtf(var + 1e-6f);
  float4 g = ((const float4*)gamma)[t];
  float4 bb = ((const float4*)beta)[t];
  float r0 = dx * rstd * g.x + bb.x;
  float r1 = dy * rstd * g.y + bb.y;
  float r2 = dz * rstd * g.z + bb.z;
  float r3 = dw * rstd * g.w + bb.w;
  if (MODE == 0) {
    ushort4 o4;
    o4.x = f2bf(r0); o4.y = f2bf(r1); o4.z = f2bf(r2); o4.w = f2bf(r3);
    ((ushort4*)(out_bf + (size_t)row * Dd))[t] = o4;
  } else {
    float4 o4 = {r0, r1, r2, r3};
    ((float4*)(out_f + (size_t)row * Dd))[t] = o4;
  }
}

// ---------------------------------------------------------------------------
extern "C" void kernel_launch(void* const* d_in, const int* in_sizes, int n_in,
                              void* d_out, int out_size, void* d_ws, size_t ws_size,
                              hipStream_t stream) {
  const float* x  = (const float*)d_in[0];
  const float* y  = (const float*)d_in[1];
  const float* Wq = (const float*)d_in[2];
  const float* bq = (const float*)d_in[3];
  const float* Wk = (const float*)d_in[4];
  const float* bk = (const float*)d_in[5];
  const float* Wv = (const float*)d_in[6];
  const float* bv = (const float*)d_in[7];
  const float* Wf = (const float*)d_in[8];
  const float* bf = (const float*)d_in[9];
  const float* g1 = (const float*)d_in[10];
  const float* b1 = (const float*)d_in[11];
  const float* g2 = (const float*)d_in[12];
  const float* b2 = (const float*)d_in[13];

  char* ws = (char*)d_ws;
  const size_t MB = 1024 * 1024;
  // workspace (88 MB). Lifetime-disjoint aliases: Obf<-yb, tb<-Qb, ub<-Kb.
  unsigned short* xb  = (unsigned short*)(ws + 0 * MB);   // live -> LN1
  unsigned short* yb  = (unsigned short*)(ws + 16 * MB);
  unsigned short* WqT = (unsigned short*)(ws + 32 * MB);
  unsigned short* WkT = (unsigned short*)(ws + 34 * MB);
  unsigned short* WvT = (unsigned short*)(ws + 36 * MB);
  unsigned short* WfT = (unsigned short*)(ws + 38 * MB);
  unsigned short* Qb  = (unsigned short*)(ws + 40 * MB);
  unsigned short* Kb  = (unsigned short*)(ws + 56 * MB);
  unsigned short* Vtb = (unsigned short*)(ws + 72 * MB);  // [B][D][c(N)]
  unsigned short* Obf = (unsigned short*)(ws + 16 * MB);  // alias yb
  unsigned short* tb  = (unsigned short*)(ws + 40 * MB);  // alias Qb
  unsigned short* ub  = (unsigned short*)(ws + 56 * MB);  // alias Kb

  prep<<<dim3(1024, 1, 6), 256, 0, stream>>>(
      x, y, xb, yb, Wq, Wk, Wv, Wf, WqT, WkT, WvT, WfT);

  gemm_qkv<<<dim3(8, 64, 3), 256, 0, stream>>>(
      xb, yb, WqT, WkT, WvT, bq, bk, bv, Qb, Kb, Vtb);

  attn_fwd<<<dim3(4, 128), 512, 0, stream>>>(Qb, Kb, Vtb, Obf);

  ln_k<0><<<Mrows, 256, 0, stream>>>(xb, Obf, g1, b1, tb, nullptr);

  gemm_ff<<<dim3(8, 64), 256, 0, stream>>>(tb, WfT, bf, tb, ub);

  ln_k<1><<<Mrows, 256, 0, stream>>>(ub, nullptr, g2, b2, nullptr, (float*)d_out);
}

// Round 16
// 196.020 us; speedup vs baseline: 1.0116x; 1.0116x over previous
//
#include <hip/hip_runtime.h>

// ---------------------------------------------------------------------------
// MultiHeadAttentionBlock: q=x@Wq; k=y@Wk; v=y@Wv; attn; +x; LN1; FF+ReLU+res;
// LN2.  B=8 N=1024 D=1024 H=16 DH=64.  All heavy math in bf16 MFMA.
// Configuration: measured-best (R10, 195.9 us).  Subsequent structural
// experiments (deeper attn tiles, 8-phase 256^2 GEMM, KV-fusion, ring
// staging, pipelined 2-phase) all regressed or were neutral — each loses
// more occupancy than its pipeline gain at this problem shape.
// ---------------------------------------------------------------------------

#define Bb 8
#define Nn 1024
#define Dd 1024
#define Hh 16
#define DH 64
#define Mrows (Bb * 1024)   // 8192

// exp(S/32) == exp2(S * log2(e)/32); fold into Q projection epilogue.
#define QSCL 0.045084220027780106f

typedef float f32x4 __attribute__((ext_vector_type(4)));
typedef __bf16 bf16x8 __attribute__((ext_vector_type(8)));
typedef unsigned int u32x4 __attribute__((ext_vector_type(4)));

#define MFMA16(acc, a, b) \
  acc = __builtin_amdgcn_mfma_f32_16x16x32_bf16((a), (b), (acc), 0, 0, 0)

__device__ __forceinline__ bf16x8 ld_frag(const void* p) {
  u32x4 v = *(const u32x4*)p;
  return __builtin_bit_cast(bf16x8, v);
}

// async global->LDS, 16B per lane (wave-uniform LDS base; per-lane global src)
__device__ __forceinline__ void gload16(const void* g, void* l) {
  __builtin_amdgcn_global_load_lds(
      (const __attribute__((address_space(1))) unsigned int*)g,
      (__attribute__((address_space(3))) unsigned int*)l, 16, 0, 0);
}

__device__ __forceinline__ unsigned short f2bf(float f) {
  return __builtin_bit_cast(unsigned short, (__bf16)f);
}
__device__ __forceinline__ float bf2f(unsigned short s) {
  unsigned int u = ((unsigned int)s) << 16;
  return __builtin_bit_cast(float, u);
}
// pack 2 f32 -> 2 bf16 in one u32 (lo=a, hi=b); no builtin on gfx950
__device__ __forceinline__ unsigned cvt_pk_bf16(float a, float b) {
  unsigned r;
  asm("v_cvt_pk_bf16_f32 %0, %1, %2" : "=v"(r) : "v"(a), "v"(b));
  return r;
}

// ---------------------------------------------------------------------------
// Fused prep: z=0 cvt x->xb, z=1 cvt y->yb, z=2..5 transpose W[z-2] -> Wt bf16
// ---------------------------------------------------------------------------
__global__ __launch_bounds__(256) void prep(
    const float* __restrict__ x, const float* __restrict__ y,
    unsigned short* __restrict__ xb, unsigned short* __restrict__ yb,
    const float* __restrict__ W0, const float* __restrict__ W1,
    const float* __restrict__ W2, const float* __restrict__ W3,
    unsigned short* __restrict__ T0, unsigned short* __restrict__ T1,
    unsigned short* __restrict__ T2, unsigned short* __restrict__ T3) {
  __shared__ float tile[32][33];
  const int z = blockIdx.z, t = threadIdx.x;
  if (z < 2) {
    const float* in = z ? y : x;
    unsigned short* out = z ? yb : xb;
    const int n4 = (Mrows * Dd) / 4;
    int i = blockIdx.x * 256 + t;
    int stride = 1024 * 256;
    for (; i < n4; i += stride) {
      float4 v = ((const float4*)in)[i];
      ushort4 o;
      o.x = f2bf(v.x); o.y = f2bf(v.y); o.z = f2bf(v.z); o.w = f2bf(v.w);
      ((ushort4*)out)[i] = o;
    }
  } else {
    const float* W = z == 2 ? W0 : z == 3 ? W1 : z == 4 ? W2 : W3;
    unsigned short* Wt = z == 2 ? T0 : z == 3 ? T1 : z == 4 ? T2 : T3;
    const int tx = t & 31, ty = t >> 5;
    const int n0 = (blockIdx.x & 31) * 32, k0 = (blockIdx.x >> 5) * 32;
#pragma unroll
    for (int i = ty; i < 32; i += 8)
      tile[i][tx] = W[(size_t)(k0 + i) * Dd + n0 + tx];
    __syncthreads();
#pragma unroll
    for (int i = ty; i < 32; i += 8)
      Wt[(size_t)(n0 + i) * Dd + k0 + tx] = f2bf(tile[tx][i]);
  }
}

// ---------------------------------------------------------------------------
// 2-phase 128x128 GEMM core (m97 structure, BK=64, XCD-swizzled grid (8,M/128))
// ---------------------------------------------------------------------------
struct GemmCtx { int m0, n0, wm, wn, lr, lk, lg, l, w; };

template <typename EpiFn>
__device__ __forceinline__ void gemm_core(
    const unsigned short* __restrict__ A, const unsigned short* __restrict__ Bt,
    int K, EpiFn epi) {
  __shared__ __attribute__((aligned(16))) unsigned short As[2][128 * 32];
  __shared__ __attribute__((aligned(16))) unsigned short Bs[2][128 * 32];
  const int bid = blockIdx.y * 8 + blockIdx.x;
  const int nwg = (gridDim.x * gridDim.y);
  const int swz = (bid & 7) * (nwg >> 3) + (bid >> 3);
  const int m0 = (swz >> 3) * 128, n0 = (swz & 7) * 128;
  const int t = threadIdx.x, w = t >> 6, l = t & 63;
  const int wm = (w >> 1) * 64, wn = (w & 1) * 64;
  const int lr = l & 15, lk = (l >> 4) * 8;
  const int rA = t >> 2, sA = (t & 3) * 8;
  char* AsB = (char*)As;
  char* BsB = (char*)Bs;
  const int wb = (w * 64) * 16;

  f32x4 acc[4][4] = {};

  for (int k0 = 0; k0 < K; k0 += 64) {
    __syncthreads();
#pragma unroll
    for (int h = 0; h < 2; ++h) {
      const int ko = k0 + h * 32;
      gload16(A + (size_t)(m0 + rA) * K + ko + sA, AsB + h * 8192 + wb);
      gload16(A + (size_t)(m0 + 64 + rA) * K + ko + sA, AsB + h * 8192 + wb + 4096);
      gload16(Bt + (size_t)(n0 + rA) * K + ko + sA, BsB + h * 8192 + wb);
      gload16(Bt + (size_t)(n0 + 64 + rA) * K + ko + sA, BsB + h * 8192 + wb + 4096);
    }
    __syncthreads();

#pragma unroll
    for (int h = 0; h < 2; ++h) {
      bf16x8 af[4], bfr[4];
#pragma unroll
      for (int i = 0; i < 4; ++i)
        af[i] = ld_frag(&As[h][(wm + i * 16 + lr) * 32 + lk]);
#pragma unroll
      for (int j = 0; j < 4; ++j)
        bfr[j] = ld_frag(&Bs[h][(wn + j * 16 + lr) * 32 + lk]);
#pragma unroll
      for (int i = 0; i < 4; ++i)
#pragma unroll
        for (int j = 0; j < 4; ++j) MFMA16(acc[i][j], af[i], bfr[j]);
    }
  }
  GemmCtx c{m0, n0, wm, wn, lr, lk, l >> 4, l, w};
  epi(acc, c);
}

// ---------------------------------------------------------------------------
// Fused Q/K/V projection GEMMs: blockIdx.z selects {Q, K, V}.
//   z=0: Qb = bf16((x@Wq + bq) * QSCL)
//   z=1: Kb = bf16(y@Wk + bk)
//   z=2: Vtb[b][d][c(n)] = bf16(y@Wv + bv)^T with column permute
//        c(n) = (n&~31)|(((n>>2)&3)<<3)|(((n>>4)&1)<<2)|(n&3)  so attn's
//        pi-ordered V A-frags are contiguous b128 reads.
// ---------------------------------------------------------------------------
__global__ __launch_bounds__(256) void gemm_qkv(
    const unsigned short* __restrict__ xb, const unsigned short* __restrict__ yb,
    const unsigned short* __restrict__ WqT, const unsigned short* __restrict__ WkT,
    const unsigned short* __restrict__ WvT,
    const float* __restrict__ bq, const float* __restrict__ bk,
    const float* __restrict__ bv,
    unsigned short* __restrict__ Qb, unsigned short* __restrict__ Kb,
    unsigned short* __restrict__ Vtb) {
  const int z = blockIdx.z;
  const unsigned short* A = (z == 0) ? xb : yb;
  const unsigned short* Bt = (z == 0) ? WqT : (z == 1) ? WkT : WvT;
  const float* bias = (z == 0) ? bq : (z == 1) ? bk : bv;
  unsigned short* Cb = (z == 0) ? Qb : Kb;

  gemm_core(A, Bt, Dd, [&](f32x4 (&acc)[4][4], GemmCtx c) {
#pragma unroll
    for (int i = 0; i < 4; ++i)
#pragma unroll
      for (int j = 0; j < 4; ++j) {
        int col = c.n0 + c.wn + j * 16 + c.lr;
        float bcol = bias[col];
        if (z == 2) {
          int brow = c.m0 + c.wm + i * 16 + c.lg * 4;
          int bi = brow >> 10, nloc = brow & 1023;
          int nperm = (nloc & ~31) | (((nloc >> 2) & 3) << 3) |
                      (((nloc >> 4) & 1) << 2);
          ushort4 o4;
          o4.x = f2bf(acc[i][j][0] + bcol);
          o4.y = f2bf(acc[i][j][1] + bcol);
          o4.z = f2bf(acc[i][j][2] + bcol);
          o4.w = f2bf(acc[i][j][3] + bcol);
          *(ushort4*)(Vtb + ((size_t)bi * Dd + col) * Nn + nperm) = o4;
        } else {
          float scl = (z == 0) ? QSCL : 1.0f;
#pragma unroll
          for (int r = 0; r < 4; ++r) {
            int row = c.m0 + c.wm + i * 16 + c.lg * 4 + r;
            Cb[(size_t)row * Dd + col] = f2bf((acc[i][j][r] + bcol) * scl);
          }
        }
      }
  });
}

// ---------------------------------------------------------------------------
// FF GEMM: Cb = bf16( bf2f(Tres) + relu(acc + bias) )
// ---------------------------------------------------------------------------
__global__ __launch_bounds__(256) void gemm_ff(
    const unsigned short* __restrict__ A, const unsigned short* __restrict__ Bt,
    const float* __restrict__ bias, const unsigned short* __restrict__ Tres,
    unsigned short* __restrict__ Cb) {
  gemm_core(A, Bt, Dd, [&](f32x4 (&acc)[4][4], GemmCtx c) {
#pragma unroll
    for (int i = 0; i < 4; ++i)
#pragma unroll
      for (int j = 0; j < 4; ++j) {
        int col = c.n0 + c.wn + j * 16 + c.lr;
        float bcol = bias[col];
#pragma unroll
        for (int r = 0; r < 4; ++r) {
          int row = c.m0 + c.wm + i * 16 + c.lg * 4 + r;
          size_t idx = (size_t)row * Dd + col;
          Cb[idx] = f2bf(bf2f(Tres[idx]) + fmaxf(acc[i][j][r] + bcol, 0.f));
        }
      }
  });
}

// ---------------------------------------------------------------------------
// Flash attention (measured-best R10 config): 1 block = 8 waves = 256 q-rows
// of one (b,h); 32 q-rows/wave; kv tiles of 64.  Swapped QK^T (S^T=mfma(K,Q))
// -> softmax fully per-lane in exp2 domain (scale folded into Q, no max
// needed); P->PV B-frag built IN-REGISTER via v_cvt_pk_bf16_f32 (pi k-slot
// packing); V A-frag one conflict-free ds_read_b128 (c(n) global permute);
// row-sums via ones-MFMA; XOR-swizzled double-buffered K/V LDS with ONE
// barrier per tile; XCD-aware block swizzle.
// ---------------------------------------------------------------------------
__global__ __launch_bounds__(512) void attn_fwd(
    const unsigned short* __restrict__ Qg, const unsigned short* __restrict__ Kg,
    const unsigned short* __restrict__ Vt, unsigned short* __restrict__ Obf) {
  __shared__ __attribute__((aligned(16))) unsigned short KVs[2][2][64 * 64];
  char* lbase = (char*)KVs;   // [buf]{K(8KB) | V(8KB)}

  const int bid = blockIdx.y * 4 + blockIdx.x;   // grid (4,128) = 512 wgs
  const int swz = (bid & 7) * 64 + (bid >> 3);
  const int q0 = (swz & 3) * 256;
  const int by = swz >> 2;
  const int b = by >> 4, h = by & 15;

  const int t = threadIdx.x, w = t >> 6, l = t & 63;
  const int lr = l & 15, lg = l >> 4;

  bf16x8 aq[2][2];
#pragma unroll
  for (int i = 0; i < 2; ++i) {
    const unsigned short* qp =
        Qg + ((size_t)b * Nn + q0 + w * 32 + i * 16 + lr) * Dd + h * DH + lg * 8;
    aq[i][0] = *(const bf16x8*)qp;
    aq[i][1] = *(const bf16x8*)(qp + 32);
  }

  u32x4 one4 = {0x3F803F80u, 0x3F803F80u, 0x3F803F80u, 0x3F803F80u};
  const bf16x8 vones = __builtin_bit_cast(bf16x8, one4);

  const size_t baseK = (size_t)b * Nn * Dd + h * DH;
  const size_t baseV = ((size_t)b * Dd + h * DH) * Nn;

  const int srow = t >> 3, sch = t & 7;
  const int sby = srow * 128 + ((sch * 16) ^ ((srow & 7) << 4));

  uint4 kA = *(const uint4*)(Kg + baseK + (size_t)srow * Dd + sch * 8);
  uint4 vA = *(const uint4*)(Vt + baseV + (size_t)srow * Nn + sch * 8);

  *(uint4*)(lbase + sby) = kA;
  *(uint4*)(lbase + 8192 + sby) = vA;
  __syncthreads();

  f32x4 oacc[4][2] = {};
  f32x4 lacc[2] = {};

  for (int kv = 0; kv < Nn / 64; ++kv) {
    char* kcur = lbase + (kv & 1) * 16384;
    char* vcur = kcur + 8192;
    const bool more = (kv + 1) < Nn / 64;
    if (more) {
      int kvo = (kv + 1) * 64;
      kA = *(const uint4*)(Kg + baseK + (size_t)(kvo + srow) * Dd + sch * 8);
      vA = *(const uint4*)(Vt + baseV + (size_t)srow * Nn + kvo + sch * 8);
    }

    f32x4 st[2][4];
    __builtin_amdgcn_s_setprio(1);
#pragma unroll
    for (int j = 0; j < 4; ++j) {
      const int kro = (j * 16 + lr) * 128;
      bf16x8 k0 = ld_frag(kcur + kro + (((lg ^ (lr & 7))) << 4));
      bf16x8 k1 = ld_frag(kcur + kro + ((((lg + 4) ^ (lr & 7))) << 4));
#pragma unroll
      for (int i = 0; i < 2; ++i) {
        f32x4 zz = {0.f, 0.f, 0.f, 0.f};
        MFMA16(zz, k0, aq[i][0]);
        MFMA16(zz, k1, aq[i][1]);
        st[i][j] = zz;
      }
    }
    __builtin_amdgcn_s_setprio(0);

#pragma unroll
    for (int i = 0; i < 2; ++i)
#pragma unroll
      for (int j = 0; j < 4; ++j) {
        st[i][j][0] = exp2f(st[i][j][0]);
        st[i][j][1] = exp2f(st[i][j][1]);
        st[i][j][2] = exp2f(st[i][j][2]);
        st[i][j][3] = exp2f(st[i][j][3]);
      }

#pragma unroll
    for (int m = 0; m < 2; ++m) {
      bf16x8 pb[2];
#pragma unroll
      for (int i = 0; i < 2; ++i) {
        u32x4 pk;
        pk[0] = cvt_pk_bf16(st[i][2 * m][0], st[i][2 * m][1]);
        pk[1] = cvt_pk_bf16(st[i][2 * m][2], st[i][2 * m][3]);
        pk[2] = cvt_pk_bf16(st[i][2 * m + 1][0], st[i][2 * m + 1][1]);
        pk[3] = cvt_pk_bf16(st[i][2 * m + 1][2], st[i][2 * m + 1][3]);
        pb[i] = __builtin_bit_cast(bf16x8, pk);
      }
      __builtin_amdgcn_s_setprio(1);
      MFMA16(lacc[0], vones, pb[0]);
      MFMA16(lacc[1], vones, pb[1]);
#pragma unroll
      for (int da = 0; da < 4; ++da) {
        const int vrow = da * 16 + lr;
        bf16x8 va = ld_frag(
            vcur + vrow * 128 + (((lg + 4 * m) ^ (vrow & 7)) << 4));
        MFMA16(oacc[da][0], va, pb[0]);
        MFMA16(oacc[da][1], va, pb[1]);
      }
      __builtin_amdgcn_s_setprio(0);
    }

    if (more) {
      char* knxt = lbase + ((kv + 1) & 1) * 16384;
      *(uint4*)(knxt + sby) = kA;
      *(uint4*)(knxt + 8192 + sby) = vA;
      __syncthreads();
    }
  }

#pragma unroll
  for (int i = 0; i < 2; ++i) {
    float rd = 1.f / lacc[i][0];
    const size_t orow = (size_t)b * Nn + q0 + w * 32 + i * 16 + lr;
#pragma unroll
    for (int da = 0; da < 4; ++da) {
      ushort4 o4;
      o4.x = f2bf(oacc[da][i][0] * rd);
      o4.y = f2bf(oacc[da][i][1] * rd);
      o4.z = f2bf(oacc[da][i][2] * rd);
      o4.w = f2bf(oacc[da][i][3] * rd);
      *(ushort4*)(Obf + orow * Dd + h * DH + da * 16 + lg * 4) = o4;
    }
  }
}

// ---------------------------------------------------------------------------
// LayerNorm over D=1024, one block (256 thr) per row.  Inputs bf16.
//   MODE 0: t = LN(X + Oin) -> bf16 out_bf
//   MODE 1: out_f = LN(X)   -> f32
// ---------------------------------------------------------------------------
template <int MODE>
__global__ __launch_bounds__(256) void ln_k(
    const unsigned short* __restrict__ X, const unsigned short* __restrict__ Oin,
    const float* __restrict__ gamma, const float* __restrict__ beta,
    unsigned short* __restrict__ out_bf, float* __restrict__ out_f) {
  __shared__ float red[8];
  const int row = blockIdx.x, t = threadIdx.x;
  ushort4 xu = ((const ushort4*)(X + (size_t)row * Dd))[t];
  float4 v = {bf2f(xu.x), bf2f(xu.y), bf2f(xu.z), bf2f(xu.w)};
  if (MODE == 0) {
    ushort4 o = ((const ushort4*)(Oin + (size_t)row * Dd))[t];
    v.x += bf2f(o.x); v.y += bf2f(o.y); v.z += bf2f(o.z); v.w += bf2f(o.w);
  }
  float s = v.x + v.y + v.z + v.w;
#pragma unroll
  for (int o = 32; o > 0; o >>= 1) s += __shfl_xor(s, o, 64);
  if ((t & 63) == 0) red[t >> 6] = s;
  __syncthreads();
  float mean = (red[0] + red[1] + red[2] + red[3]) * (1.f / 1024.f);
  float dx = v.x - mean, dy = v.y - mean, dz = v.z - mean, dw = v.w - mean;
  float s2 = dx * dx + dy * dy + dz * dz + dw * dw;
#pragma unroll
  for (int o = 32; o > 0; o >>= 1) s2 += __shfl_xor(s2, o, 64);
  if ((t & 63) == 0) red[4 + (t >> 6)] = s2;
  __syncthreads();
  float var = (red[4] + red[5] + red[6] + red[7]) * (1.f / 1024.f);
  float rstd = rsqrtf(var + 1e-6f);
  float4 g = ((const float4*)gamma)[t];
  float4 bb = ((const float4*)beta)[t];
  float r0 = dx * rstd * g.x + bb.x;
  float r1 = dy * rstd * g.y + bb.y;
  float r2 = dz * rstd * g.z + bb.z;
  float r3 = dw * rstd * g.w + bb.w;
  if (MODE == 0) {
    ushort4 o4;
    o4.x = f2bf(r0); o4.y = f2bf(r1); o4.z = f2bf(r2); o4.w = f2bf(r3);
    ((ushort4*)(out_bf + (size_t)row * Dd))[t] = o4;
  } else {
    float4 o4 = {r0, r1, r2, r3};
    ((float4*)(out_f + (size_t)row * Dd))[t] = o4;
  }
}

// ---------------------------------------------------------------------------
extern "C" void kernel_launch(void* const* d_in, const int* in_sizes, int n_in,
                              void* d_out, int out_size, void* d_ws, size_t ws_size,
                              hipStream_t stream) {
  const float* x  = (const float*)d_in[0];
  const float* y  = (const float*)d_in[1];
  const float* Wq = (const float*)d_in[2];
  const float* bq = (const float*)d_in[3];
  const float* Wk = (const float*)d_in[4];
  const float* bk = (const float*)d_in[5];
  const float* Wv = (const float*)d_in[6];
  const float* bv = (const float*)d_in[7];
  const float* Wf = (const float*)d_in[8];
  const float* bf = (const float*)d_in[9];
  const float* g1 = (const float*)d_in[10];
  const float* b1 = (const float*)d_in[11];
  const float* g2 = (const float*)d_in[12];
  const float* b2 = (const float*)d_in[13];

  char* ws = (char*)d_ws;
  const size_t MB = 1024 * 1024;
  // workspace (88 MB). Lifetime-disjoint aliases: Obf<-yb, tb<-Qb, ub<-Kb.
  unsigned short* xb  = (unsigned short*)(ws + 0 * MB);   // live -> LN1
  unsigned short* yb  = (unsigned short*)(ws + 16 * MB);
  unsigned short* WqT = (unsigned short*)(ws + 32 * MB);
  unsigned short* WkT = (unsigned short*)(ws + 34 * MB);
  unsigned short* WvT = (unsigned short*)(ws + 36 * MB);
  unsigned short* WfT = (unsigned short*)(ws + 38 * MB);
  unsigned short* Qb  = (unsigned short*)(ws + 40 * MB);
  unsigned short* Kb  = (unsigned short*)(ws + 56 * MB);
  unsigned short* Vtb = (unsigned short*)(ws + 72 * MB);  // [B][D][c(N)]
  unsigned short* Obf = (unsigned short*)(ws + 16 * MB);  // alias yb
  unsigned short* tb  = (unsigned short*)(ws + 40 * MB);  // alias Qb
  unsigned short* ub  = (unsigned short*)(ws + 56 * MB);  // alias Kb

  prep<<<dim3(1024, 1, 6), 256, 0, stream>>>(
      x, y, xb, yb, Wq, Wk, Wv, Wf, WqT, WkT, WvT, WfT);

  gemm_qkv<<<dim3(8, 64, 3), 256, 0, stream>>>(
      xb, yb, WqT, WkT, WvT, bq, bk, bv, Qb, Kb, Vtb);

  attn_fwd<<<dim3(4, 128), 512, 0, stream>>>(Qb, Kb, Vtb, Obf);

  ln_k<0><<<Mrows, 256, 0, stream>>>(xb, Obf, g1, b1, tb, nullptr);

  gemm_ff<<<dim3(8, 64), 256, 0, stream>>>(tb, WfT, bf, tb, ub);

  ln_k<1><<<Mrows, 256, 0, stream>>>(ub, nullptr, g2, b2, nullptr, (float*)d_out);
}

// Round 17
// 191.588 us; speedup vs baseline: 1.0350x; 1.0231x over previous
//
#include <hip/hip_runtime.h>

// ---------------------------------------------------------------------------
// MultiHeadAttentionBlock: q=x@Wq; k=y@Wk; v=y@Wv; attn; +x; LN1; FF+ReLU+res;
// LN2.  B=8 N=1024 D=1024 H=16 DH=64.  All heavy math in bf16 MFMA.
// GEMMs: 128x128 2-phase m97 structure, 8 waves x (64x32) sub-tiles with
// __launch_bounds__(512,4) to stay under the 128-unified-reg granule
// (84 VGPR + 64 AGPR = 148 was forcing 2 waves/SIMD; 4x2 acc = 32 AGPR).
// ---------------------------------------------------------------------------

#define Bb 8
#define Nn 1024
#define Dd 1024
#define Hh 16
#define DH 64
#define Mrows (Bb * 1024)   // 8192

// exp(S/32) == exp2(S * log2(e)/32); fold into Q projection epilogue.
#define QSCL 0.045084220027780106f

typedef float f32x4 __attribute__((ext_vector_type(4)));
typedef __bf16 bf16x8 __attribute__((ext_vector_type(8)));
typedef unsigned int u32x4 __attribute__((ext_vector_type(4)));

#define MFMA16(acc, a, b) \
  acc = __builtin_amdgcn_mfma_f32_16x16x32_bf16((a), (b), (acc), 0, 0, 0)

__device__ __forceinline__ bf16x8 ld_frag(const void* p) {
  u32x4 v = *(const u32x4*)p;
  return __builtin_bit_cast(bf16x8, v);
}

// async global->LDS, 16B per lane (wave-uniform LDS base; per-lane global src)
__device__ __forceinline__ void gload16(const void* g, void* l) {
  __builtin_amdgcn_global_load_lds(
      (const __attribute__((address_space(1))) unsigned int*)g,
      (__attribute__((address_space(3))) unsigned int*)l, 16, 0, 0);
}

__device__ __forceinline__ unsigned short f2bf(float f) {
  return __builtin_bit_cast(unsigned short, (__bf16)f);
}
__device__ __forceinline__ float bf2f(unsigned short s) {
  unsigned int u = ((unsigned int)s) << 16;
  return __builtin_bit_cast(float, u);
}
// pack 2 f32 -> 2 bf16 in one u32 (lo=a, hi=b); no builtin on gfx950
__device__ __forceinline__ unsigned cvt_pk_bf16(float a, float b) {
  unsigned r;
  asm("v_cvt_pk_bf16_f32 %0, %1, %2" : "=v"(r) : "v"(a), "v"(b));
  return r;
}

// ---------------------------------------------------------------------------
// Fused prep: z=0 cvt x->xb, z=1 cvt y->yb, z=2..5 transpose W[z-2] -> Wt bf16
// ---------------------------------------------------------------------------
__global__ __launch_bounds__(256) void prep(
    const float* __restrict__ x, const float* __restrict__ y,
    unsigned short* __restrict__ xb, unsigned short* __restrict__ yb,
    const float* __restrict__ W0, const float* __restrict__ W1,
    const float* __restrict__ W2, const float* __restrict__ W3,
    unsigned short* __restrict__ T0, unsigned short* __restrict__ T1,
    unsigned short* __restrict__ T2, unsigned short* __restrict__ T3) {
  __shared__ float tile[32][33];
  const int z = blockIdx.z, t = threadIdx.x;
  if (z < 2) {
    const float* in = z ? y : x;
    unsigned short* out = z ? yb : xb;
    const int n4 = (Mrows * Dd) / 4;
    int i = blockIdx.x * 256 + t;
    int stride = 1024 * 256;
    for (; i < n4; i += stride) {
      float4 v = ((const float4*)in)[i];
      ushort4 o;
      o.x = f2bf(v.x); o.y = f2bf(v.y); o.z = f2bf(v.z); o.w = f2bf(v.w);
      ((ushort4*)out)[i] = o;
    }
  } else {
    const float* W = z == 2 ? W0 : z == 3 ? W1 : z == 4 ? W2 : W3;
    unsigned short* Wt = z == 2 ? T0 : z == 3 ? T1 : z == 4 ? T2 : T3;
    const int tx = t & 31, ty = t >> 5;
    const int n0 = (blockIdx.x & 31) * 32, k0 = (blockIdx.x >> 5) * 32;
#pragma unroll
    for (int i = ty; i < 32; i += 8)
      tile[i][tx] = W[(size_t)(k0 + i) * Dd + n0 + tx];
    __syncthreads();
#pragma unroll
    for (int i = ty; i < 32; i += 8)
      Wt[(size_t)(n0 + i) * Dd + k0 + tx] = f2bf(tile[tx][i]);
  }
}

// ---------------------------------------------------------------------------
// 2-phase 128x128 GEMM core — 8 waves (2M x 4N), 64x32 per wave, BK=64,
// XCD-swizzled grid (8, M/128).  LDS 32 KB linear (unchanged layout).
// acc = f32x4[4][2] (32 AGPR) so unified regs fit the <=128 granule at
// __launch_bounds__(512,4) -> 4 waves/SIMD (was 2 at 148 regs).
// ---------------------------------------------------------------------------
struct GemmCtx { int m0, n0, wm, wn, lr, lk, lg, l, w; };

template <typename EpiFn>
__device__ __forceinline__ void gemm_core(
    const unsigned short* __restrict__ A, const unsigned short* __restrict__ Bt,
    int K, EpiFn epi) {
  __shared__ __attribute__((aligned(16))) unsigned short As[2][128 * 32];
  __shared__ __attribute__((aligned(16))) unsigned short Bs[2][128 * 32];
  const int bid = blockIdx.y * 8 + blockIdx.x;
  const int nwg = (gridDim.x * gridDim.y);
  const int swz = (bid & 7) * (nwg >> 3) + (bid >> 3);
  const int m0 = (swz >> 3) * 128, n0 = (swz & 7) * 128;
  const int t = threadIdx.x, wid = t >> 6, l = t & 63;
  const int wm = (wid >> 2) * 64, wn = (wid & 3) * 32;
  const int lr = l & 15, lk = (l >> 4) * 8;
  const int rA = t >> 2, sA = (t & 3) * 8;   // 512 chunks of 16B cover 8KB
  char* AsB = (char*)As;
  char* BsB = (char*)Bs;
  const int wb = wid * 1024;                 // wave-uniform LDS byte base

  f32x4 acc[4][2] = {};

  for (int k0 = 0; k0 < K; k0 += 64) {
    __syncthreads();
#pragma unroll
    for (int h = 0; h < 2; ++h) {
      const int ko = k0 + h * 32;
      gload16(A + (size_t)(m0 + rA) * K + ko + sA, AsB + h * 8192 + wb);
      gload16(Bt + (size_t)(n0 + rA) * K + ko + sA, BsB + h * 8192 + wb);
    }
    __syncthreads();

#pragma unroll
    for (int h = 0; h < 2; ++h) {
      bf16x8 af[4], bfr[2];
#pragma unroll
      for (int i = 0; i < 4; ++i)
        af[i] = ld_frag(&As[h][(wm + i * 16 + lr) * 32 + lk]);
#pragma unroll
      for (int j = 0; j < 2; ++j)
        bfr[j] = ld_frag(&Bs[h][(wn + j * 16 + lr) * 32 + lk]);
#pragma unroll
      for (int i = 0; i < 4; ++i)
#pragma unroll
        for (int j = 0; j < 2; ++j) MFMA16(acc[i][j], af[i], bfr[j]);
    }
  }
  GemmCtx c{m0, n0, wm, wn, lr, lk, l >> 4, l, wid};
  epi(acc, c);
}

// ---------------------------------------------------------------------------
// Fused Q/K/V projection GEMMs: blockIdx.z selects {Q, K, V}.
//   z=0: Qb = bf16((x@Wq + bq) * QSCL)
//   z=1: Kb = bf16(y@Wk + bk)
//   z=2: Vtb[b][d][c(n)] = bf16(y@Wv + bv)^T with column permute
//        c(n) = (n&~31)|(((n>>2)&3)<<3)|(((n>>4)&1)<<2)|(n&3)  so attn's
//        pi-ordered V A-frags are contiguous b128 reads.
// ---------------------------------------------------------------------------
__global__ __launch_bounds__(512, 4) void gemm_qkv(
    const unsigned short* __restrict__ xb, const unsigned short* __restrict__ yb,
    const unsigned short* __restrict__ WqT, const unsigned short* __restrict__ WkT,
    const unsigned short* __restrict__ WvT,
    const float* __restrict__ bq, const float* __restrict__ bk,
    const float* __restrict__ bv,
    unsigned short* __restrict__ Qb, unsigned short* __restrict__ Kb,
    unsigned short* __restrict__ Vtb) {
  const int z = blockIdx.z;
  const unsigned short* A = (z == 0) ? xb : yb;
  const unsigned short* Bt = (z == 0) ? WqT : (z == 1) ? WkT : WvT;
  const float* bias = (z == 0) ? bq : (z == 1) ? bk : bv;
  unsigned short* Cb = (z == 0) ? Qb : Kb;

  gemm_core(A, Bt, Dd, [&](f32x4 (&acc)[4][2], GemmCtx c) {
#pragma unroll
    for (int i = 0; i < 4; ++i)
#pragma unroll
      for (int j = 0; j < 2; ++j) {
        int col = c.n0 + c.wn + j * 16 + c.lr;
        float bcol = bias[col];
        if (z == 2) {
          int brow = c.m0 + c.wm + i * 16 + c.lg * 4;
          int bi = brow >> 10, nloc = brow & 1023;
          int nperm = (nloc & ~31) | (((nloc >> 2) & 3) << 3) |
                      (((nloc >> 4) & 1) << 2);
          ushort4 o4;
          o4.x = f2bf(acc[i][j][0] + bcol);
          o4.y = f2bf(acc[i][j][1] + bcol);
          o4.z = f2bf(acc[i][j][2] + bcol);
          o4.w = f2bf(acc[i][j][3] + bcol);
          *(ushort4*)(Vtb + ((size_t)bi * Dd + col) * Nn + nperm) = o4;
        } else {
          float scl = (z == 0) ? QSCL : 1.0f;
#pragma unroll
          for (int r = 0; r < 4; ++r) {
            int row = c.m0 + c.wm + i * 16 + c.lg * 4 + r;
            Cb[(size_t)row * Dd + col] = f2bf((acc[i][j][r] + bcol) * scl);
          }
        }
      }
  });
}

// ---------------------------------------------------------------------------
// FF GEMM: Cb = bf16( bf2f(Tres) + relu(acc + bias) )
// ---------------------------------------------------------------------------
__global__ __launch_bounds__(512, 4) void gemm_ff(
    const unsigned short* __restrict__ A, const unsigned short* __restrict__ Bt,
    const float* __restrict__ bias, const unsigned short* __restrict__ Tres,
    unsigned short* __restrict__ Cb) {
  gemm_core(A, Bt, Dd, [&](f32x4 (&acc)[4][2], GemmCtx c) {
#pragma unroll
    for (int i = 0; i < 4; ++i)
#pragma unroll
      for (int j = 0; j < 2; ++j) {
        int col = c.n0 + c.wn + j * 16 + c.lr;
        float bcol = bias[col];
#pragma unroll
        for (int r = 0; r < 4; ++r) {
          int row = c.m0 + c.wm + i * 16 + c.lg * 4 + r;
          size_t idx = (size_t)row * Dd + col;
          Cb[idx] = f2bf(bf2f(Tres[idx]) + fmaxf(acc[i][j][r] + bcol, 0.f));
        }
      }
  });
}

// ---------------------------------------------------------------------------
// Flash attention (measured-best R10 config): 1 block = 8 waves = 256 q-rows
// of one (b,h); 32 q-rows/wave; kv tiles of 64.  Swapped QK^T (S^T=mfma(K,Q))
// -> softmax fully per-lane in exp2 domain (scale folded into Q, no max
// needed); P->PV B-frag built IN-REGISTER via v_cvt_pk_bf16_f32 (pi k-slot
// packing); V A-frag one conflict-free ds_read_b128 (c(n) global permute);
// row-sums via ones-MFMA; XOR-swizzled double-buffered K/V LDS with ONE
// barrier per tile; XCD-aware block swizzle.
// ---------------------------------------------------------------------------
__global__ __launch_bounds__(512) void attn_fwd(
    const unsigned short* __restrict__ Qg, const unsigned short* __restrict__ Kg,
    const unsigned short* __restrict__ Vt, unsigned short* __restrict__ Obf) {
  __shared__ __attribute__((aligned(16))) unsigned short KVs[2][2][64 * 64];
  char* lbase = (char*)KVs;   // [buf]{K(8KB) | V(8KB)}

  const int bid = blockIdx.y * 4 + blockIdx.x;   // grid (4,128) = 512 wgs
  const int swz = (bid & 7) * 64 + (bid >> 3);
  const int q0 = (swz & 3) * 256;
  const int by = swz >> 2;
  const int b = by >> 4, h = by & 15;

  const int t = threadIdx.x, w = t >> 6, l = t & 63;
  const int lr = l & 15, lg = l >> 4;

  bf16x8 aq[2][2];
#pragma unroll
  for (int i = 0; i < 2; ++i) {
    const unsigned short* qp =
        Qg + ((size_t)b * Nn + q0 + w * 32 + i * 16 + lr) * Dd + h * DH + lg * 8;
    aq[i][0] = *(const bf16x8*)qp;
    aq[i][1] = *(const bf16x8*)(qp + 32);
  }

  u32x4 one4 = {0x3F803F80u, 0x3F803F80u, 0x3F803F80u, 0x3F803F80u};
  const bf16x8 vones = __builtin_bit_cast(bf16x8, one4);

  const size_t baseK = (size_t)b * Nn * Dd + h * DH;
  const size_t baseV = ((size_t)b * Dd + h * DH) * Nn;

  const int srow = t >> 3, sch = t & 7;
  const int sby = srow * 128 + ((sch * 16) ^ ((srow & 7) << 4));

  uint4 kA = *(const uint4*)(Kg + baseK + (size_t)srow * Dd + sch * 8);
  uint4 vA = *(const uint4*)(Vt + baseV + (size_t)srow * Nn + sch * 8);

  *(uint4*)(lbase + sby) = kA;
  *(uint4*)(lbase + 8192 + sby) = vA;
  __syncthreads();

  f32x4 oacc[4][2] = {};
  f32x4 lacc[2] = {};

  for (int kv = 0; kv < Nn / 64; ++kv) {
    char* kcur = lbase + (kv & 1) * 16384;
    char* vcur = kcur + 8192;
    const bool more = (kv + 1) < Nn / 64;
    if (more) {
      int kvo = (kv + 1) * 64;
      kA = *(const uint4*)(Kg + baseK + (size_t)(kvo + srow) * Dd + sch * 8);
      vA = *(const uint4*)(Vt + baseV + (size_t)srow * Nn + kvo + sch * 8);
    }

    f32x4 st[2][4];
    __builtin_amdgcn_s_setprio(1);
#pragma unroll
    for (int j = 0; j < 4; ++j) {
      const int kro = (j * 16 + lr) * 128;
      bf16x8 k0 = ld_frag(kcur + kro + (((lg ^ (lr & 7))) << 4));
      bf16x8 k1 = ld_frag(kcur + kro + ((((lg + 4) ^ (lr & 7))) << 4));
#pragma unroll
      for (int i = 0; i < 2; ++i) {
        f32x4 zz = {0.f, 0.f, 0.f, 0.f};
        MFMA16(zz, k0, aq[i][0]);
        MFMA16(zz, k1, aq[i][1]);
        st[i][j] = zz;
      }
    }
    __builtin_amdgcn_s_setprio(0);

#pragma unroll
    for (int i = 0; i < 2; ++i)
#pragma unroll
      for (int j = 0; j < 4; ++j) {
        st[i][j][0] = exp2f(st[i][j][0]);
        st[i][j][1] = exp2f(st[i][j][1]);
        st[i][j][2] = exp2f(st[i][j][2]);
        st[i][j][3] = exp2f(st[i][j][3]);
      }

#pragma unroll
    for (int m = 0; m < 2; ++m) {
      bf16x8 pb[2];
#pragma unroll
      for (int i = 0; i < 2; ++i) {
        u32x4 pk;
        pk[0] = cvt_pk_bf16(st[i][2 * m][0], st[i][2 * m][1]);
        pk[1] = cvt_pk_bf16(st[i][2 * m][2], st[i][2 * m][3]);
        pk[2] = cvt_pk_bf16(st[i][2 * m + 1][0], st[i][2 * m + 1][1]);
        pk[3] = cvt_pk_bf16(st[i][2 * m + 1][2], st[i][2 * m + 1][3]);
        pb[i] = __builtin_bit_cast(bf16x8, pk);
      }
      __builtin_amdgcn_s_setprio(1);
      MFMA16(lacc[0], vones, pb[0]);
      MFMA16(lacc[1], vones, pb[1]);
#pragma unroll
      for (int da = 0; da < 4; ++da) {
        const int vrow = da * 16 + lr;
        bf16x8 va = ld_frag(
            vcur + vrow * 128 + (((lg + 4 * m) ^ (vrow & 7)) << 4));
        MFMA16(oacc[da][0], va, pb[0]);
        MFMA16(oacc[da][1], va, pb[1]);
      }
      __builtin_amdgcn_s_setprio(0);
    }

    if (more) {
      char* knxt = lbase + ((kv + 1) & 1) * 16384;
      *(uint4*)(knxt + sby) = kA;
      *(uint4*)(knxt + 8192 + sby) = vA;
      __syncthreads();
    }
  }

#pragma unroll
  for (int i = 0; i < 2; ++i) {
    float rd = 1.f / lacc[i][0];
    const size_t orow = (size_t)b * Nn + q0 + w * 32 + i * 16 + lr;
#pragma unroll
    for (int da = 0; da < 4; ++da) {
      ushort4 o4;
      o4.x = f2bf(oacc[da][i][0] * rd);
      o4.y = f2bf(oacc[da][i][1] * rd);
      o4.z = f2bf(oacc[da][i][2] * rd);
      o4.w = f2bf(oacc[da][i][3] * rd);
      *(ushort4*)(Obf + orow * Dd + h * DH + da * 16 + lg * 4) = o4;
    }
  }
}

// ---------------------------------------------------------------------------
// LayerNorm over D=1024, one block (256 thr) per row.  Inputs bf16.
//   MODE 0: t = LN(X + Oin) -> bf16 out_bf
//   MODE 1: out_f = LN(X)   -> f32
// ---------------------------------------------------------------------------
template <int MODE>
__global__ __launch_bounds__(256) void ln_k(
    const unsigned short* __restrict__ X, const unsigned short* __restrict__ Oin,
    const float* __restrict__ gamma, const float* __restrict__ beta,
    unsigned short* __restrict__ out_bf, float* __restrict__ out_f) {
  __shared__ float red[8];
  const int row = blockIdx.x, t = threadIdx.x;
  ushort4 xu = ((const ushort4*)(X + (size_t)row * Dd))[t];
  float4 v = {bf2f(xu.x), bf2f(xu.y), bf2f(xu.z), bf2f(xu.w)};
  if (MODE == 0) {
    ushort4 o = ((const ushort4*)(Oin + (size_t)row * Dd))[t];
    v.x += bf2f(o.x); v.y += bf2f(o.y); v.z += bf2f(o.z); v.w += bf2f(o.w);
  }
  float s = v.x + v.y + v.z + v.w;
#pragma unroll
  for (int o = 32; o > 0; o >>= 1) s += __shfl_xor(s, o, 64);
  if ((t & 63) == 0) red[t >> 6] = s;
  __syncthreads();
  float mean = (red[0] + red[1] + red[2] + red[3]) * (1.f / 1024.f);
  float dx = v.x - mean, dy = v.y - mean, dz = v.z - mean, dw = v.w - mean;
  float s2 = dx * dx + dy * dy + dz * dz + dw * dw;
#pragma unroll
  for (int o = 32; o > 0; o >>= 1) s2 += __shfl_xor(s2, o, 64);
  if ((t & 63) == 0) red[4 + (t >> 6)] = s2;
  __syncthreads();
  float var = (red[4] + red[5] + red[6] + red[7]) * (1.f / 1024.f);
  float rstd = rsqrtf(var + 1e-6f);
  float4 g = ((const float4*)gamma)[t];
  float4 bb = ((const float4*)beta)[t];
  float r0 = dx * rstd * g.x + bb.x;
  float r1 = dy * rstd * g.y + bb.y;
  float r2 = dz * rstd * g.z + bb.z;
  float r3 = dw * rstd * g.w + bb.w;
  if (MODE == 0) {
    ushort4 o4;
    o4.x = f2bf(r0); o4.y = f2bf(r1); o4.z = f2bf(r2); o4.w = f2bf(r3);
    ((ushort4*)(out_bf + (size_t)row * Dd))[t] = o4;
  } else {
    float4 o4 = {r0, r1, r2, r3};
    ((float4*)(out_f + (size_t)row * Dd))[t] = o4;
  }
}

// ---------------------------------------------------------------------------
extern "C" void kernel_launch(void* const* d_in, const int* in_sizes, int n_in,
                              void* d_out, int out_size, void* d_ws, size_t ws_size,
                              hipStream_t stream) {
  const float* x  = (const float*)d_in[0];
  const float* y  = (const float*)d_in[1];
  const float* Wq = (const float*)d_in[2];
  const float* bq = (const float*)d_in[3];
  const float* Wk = (const float*)d_in[4];
  const float* bk = (const float*)d_in[5];
  const float* Wv = (const float*)d_in[6];
  const float* bv = (const float*)d_in[7];
  const float* Wf = (const float*)d_in[8];
  const float* bf = (const float*)d_in[9];
  const float* g1 = (const float*)d_in[10];
  const float* b1 = (const float*)d_in[11];
  const float* g2 = (const float*)d_in[12];
  const float* b2 = (const float*)d_in[13];

  char* ws = (char*)d_ws;
  const size_t MB = 1024 * 1024;
  // workspace (88 MB). Lifetime-disjoint aliases: Obf<-yb, tb<-Qb, ub<-Kb.
  unsigned short* xb  = (unsigned short*)(ws + 0 * MB);   // live -> LN1
  unsigned short* yb  = (unsigned short*)(ws + 16 * MB);
  unsigned short* WqT = (unsigned short*)(ws + 32 * MB);
  unsigned short* WkT = (unsigned short*)(ws + 34 * MB);
  unsigned short* WvT = (unsigned short*)(ws + 36 * MB);
  unsigned short* WfT = (unsigned short*)(ws + 38 * MB);
  unsigned short* Qb  = (unsigned short*)(ws + 40 * MB);
  unsigned short* Kb  = (unsigned short*)(ws + 56 * MB);
  unsigned short* Vtb = (unsigned short*)(ws + 72 * MB);  // [B][D][c(N)]
  unsigned short* Obf = (unsigned short*)(ws + 16 * MB);  // alias yb
  unsigned short* tb  = (unsigned short*)(ws + 40 * MB);  // alias Qb
  unsigned short* ub  = (unsigned short*)(ws + 56 * MB);  // alias Kb

  prep<<<dim3(1024, 1, 6), 256, 0, stream>>>(
      x, y, xb, yb, Wq, Wk, Wv, Wf, WqT, WkT, WvT, WfT);

  gemm_qkv<<<dim3(8, 64, 3), 512, 0, stream>>>(
      xb, yb, WqT, WkT, WvT, bq, bk, bv, Qb, Kb, Vtb);

  attn_fwd<<<dim3(4, 128), 512, 0, stream>>>(Qb, Kb, Vtb, Obf);

  ln_k<0><<<Mrows, 256, 0, stream>>>(xb, Obf, g1, b1, tb, nullptr);

  gemm_ff<<<dim3(8, 64), 512, 0, stream>>>(tb, WfT, bf, tb, ub);

  ln_k<1><<<Mrows, 256, 0, stream>>>(ub, nullptr, g2, b2, nullptr, (float*)d_out);
}

// Round 18
// 185.428 us; speedup vs baseline: 1.0694x; 1.0332x over previous
//
#include <hip/hip_runtime.h>

// ---------------------------------------------------------------------------
// MultiHeadAttentionBlock: q=x@Wq; k=y@Wk; v=y@Wv; attn; +x; LN1; FF+ReLU+res;
// LN2.  B=8 N=1024 D=1024 H=16 DH=64.  All heavy math in bf16 MFMA.
// GEMMs: 128x128 2-phase, 8 waves x (64x32), <=128 unified regs (4 w/SIMD),
// LDS rows 128B with chunk^=(row&7) XOR swizzle (conflict-free ds_read_b128;
// global source pre-swizzled for the linear global_load_lds dest).
// ---------------------------------------------------------------------------

#define Bb 8
#define Nn 1024
#define Dd 1024
#define Hh 16
#define DH 64
#define Mrows (Bb * 1024)   // 8192

// exp(S/32) == exp2(S * log2(e)/32); fold into Q projection epilogue.
#define QSCL 0.045084220027780106f

typedef float f32x4 __attribute__((ext_vector_type(4)));
typedef __bf16 bf16x8 __attribute__((ext_vector_type(8)));
typedef unsigned int u32x4 __attribute__((ext_vector_type(4)));

#define MFMA16(acc, a, b) \
  acc = __builtin_amdgcn_mfma_f32_16x16x32_bf16((a), (b), (acc), 0, 0, 0)

__device__ __forceinline__ bf16x8 ld_frag(const void* p) {
  u32x4 v = *(const u32x4*)p;
  return __builtin_bit_cast(bf16x8, v);
}

// async global->LDS, 16B per lane (wave-uniform LDS base; per-lane global src)
__device__ __forceinline__ void gload16(const void* g, void* l) {
  __builtin_amdgcn_global_load_lds(
      (const __attribute__((address_space(1))) unsigned int*)g,
      (__attribute__((address_space(3))) unsigned int*)l, 16, 0, 0);
}

__device__ __forceinline__ unsigned short f2bf(float f) {
  return __builtin_bit_cast(unsigned short, (__bf16)f);
}
__device__ __forceinline__ float bf2f(unsigned short s) {
  unsigned int u = ((unsigned int)s) << 16;
  return __builtin_bit_cast(float, u);
}
// pack 2 f32 -> 2 bf16 in one u32 (lo=a, hi=b); no builtin on gfx950
__device__ __forceinline__ unsigned cvt_pk_bf16(float a, float b) {
  unsigned r;
  asm("v_cvt_pk_bf16_f32 %0, %1, %2" : "=v"(r) : "v"(a), "v"(b));
  return r;
}

// ---------------------------------------------------------------------------
// Fused prep: z=0 cvt x->xb, z=1 cvt y->yb, z=2..5 transpose W[z-2] -> Wt bf16
// ---------------------------------------------------------------------------
__global__ __launch_bounds__(256) void prep(
    const float* __restrict__ x, const float* __restrict__ y,
    unsigned short* __restrict__ xb, unsigned short* __restrict__ yb,
    const float* __restrict__ W0, const float* __restrict__ W1,
    const float* __restrict__ W2, const float* __restrict__ W3,
    unsigned short* __restrict__ T0, unsigned short* __restrict__ T1,
    unsigned short* __restrict__ T2, unsigned short* __restrict__ T3) {
  __shared__ float tile[32][33];
  const int z = blockIdx.z, t = threadIdx.x;
  if (z < 2) {
    const float* in = z ? y : x;
    unsigned short* out = z ? yb : xb;
    const int n4 = (Mrows * Dd) / 4;
    int i = blockIdx.x * 256 + t;
    int stride = 1024 * 256;
    for (; i < n4; i += stride) {
      float4 v = ((const float4*)in)[i];
      ushort4 o;
      o.x = f2bf(v.x); o.y = f2bf(v.y); o.z = f2bf(v.z); o.w = f2bf(v.w);
      ((ushort4*)out)[i] = o;
    }
  } else {
    const float* W = z == 2 ? W0 : z == 3 ? W1 : z == 4 ? W2 : W3;
    unsigned short* Wt = z == 2 ? T0 : z == 3 ? T1 : z == 4 ? T2 : T3;
    const int tx = t & 31, ty = t >> 5;
    const int n0 = (blockIdx.x & 31) * 32, k0 = (blockIdx.x >> 5) * 32;
#pragma unroll
    for (int i = ty; i < 32; i += 8)
      tile[i][tx] = W[(size_t)(k0 + i) * Dd + n0 + tx];
    __syncthreads();
#pragma unroll
    for (int i = ty; i < 32; i += 8)
      Wt[(size_t)(n0 + i) * Dd + k0 + tx] = f2bf(tile[tx][i]);
  }
}

// ---------------------------------------------------------------------------
// 2-phase 128x128 GEMM core — 8 waves (2M x 4N), 64x32 per wave, BK=64.
// LDS: A,B each 128 rows x 128B (full BK per row), XOR-swizzled
// (LDS(row,pos) holds global k-chunk pos^(row&7)); staged via gload16 with
// pre-swizzled global source; ds_read_b128 at ((g)^(row&7))<<4 -> 2 rows per
// bank segment = conflict-free (m136: 2-way is free).  32 KB LDS total.
// __launch_bounds__(512,4): <=128 unified regs -> 4 waves/SIMD.
// ---------------------------------------------------------------------------
struct GemmCtx { int m0, n0, wm, wn, lr, lk, lg, l, w; };

template <typename EpiFn>
__device__ __forceinline__ void gemm_core(
    const unsigned short* __restrict__ A, const unsigned short* __restrict__ Bt,
    int K, EpiFn epi) {
  __shared__ __attribute__((aligned(16))) unsigned short As[128 * 64];
  __shared__ __attribute__((aligned(16))) unsigned short Bs[128 * 64];
  const int bid = blockIdx.y * 8 + blockIdx.x;
  const int nwg = (gridDim.x * gridDim.y);
  const int swz = (bid & 7) * (nwg >> 3) + (bid >> 3);
  const int m0 = (swz >> 3) * 128, n0 = (swz & 7) * 128;
  const int t = threadIdx.x, wid = t >> 6, l = t & 63;
  const int wm = (wid >> 2) * 64, wn = (wid & 3) * 32;
  const int lr = l & 15, lg = l >> 4;
  // staging: call c covers LDS rows c*64 + (t>>3), chunk position t&7;
  // global k-chunk fetched = pos ^ (row&7)  (pre-swizzled source, rule #21)
  const int srow = t >> 3, sch = t & 7;
  char* AsB = (char*)As;
  char* BsB = (char*)Bs;
  const int wb = wid * 1024;                 // wave-uniform LDS byte base

  f32x4 acc[4][2] = {};

  for (int k0 = 0; k0 < K; k0 += 64) {
    __syncthreads();
#pragma unroll
    for (int c = 0; c < 2; ++c) {
      const int row = c * 64 + srow;
      const int gch = sch ^ (row & 7);
      gload16(A + (size_t)(m0 + row) * K + k0 + gch * 8, AsB + c * 8192 + wb);
      gload16(Bt + (size_t)(n0 + row) * K + k0 + gch * 8, BsB + c * 8192 + wb);
    }
    __syncthreads();

#pragma unroll
    for (int h = 0; h < 2; ++h) {
      bf16x8 af[4], bfr[2];
#pragma unroll
      for (int i = 0; i < 4; ++i) {
        const int ra = wm + i * 16 + lr;
        af[i] = ld_frag(AsB + ra * 128 + (((h * 4 + lg) ^ (ra & 7)) << 4));
      }
#pragma unroll
      for (int j = 0; j < 2; ++j) {
        const int rb = wn + j * 16 + lr;
        bfr[j] = ld_frag(BsB + rb * 128 + (((h * 4 + lg) ^ (rb & 7)) << 4));
      }
#pragma unroll
      for (int i = 0; i < 4; ++i)
#pragma unroll
        for (int j = 0; j < 2; ++j) MFMA16(acc[i][j], af[i], bfr[j]);
    }
  }
  GemmCtx c{m0, n0, wm, wn, lr, lg * 8, l >> 4, l, wid};
  epi(acc, c);
}

// ---------------------------------------------------------------------------
// Fused Q/K/V projection GEMMs: blockIdx.z selects {Q, K, V}.
//   z=0: Qb = bf16((x@Wq + bq) * QSCL)
//   z=1: Kb = bf16(y@Wk + bk)
//   z=2: Vtb[b][d][c(n)] = bf16(y@Wv + bv)^T with column permute
//        c(n) = (n&~31)|(((n>>2)&3)<<3)|(((n>>4)&1)<<2)|(n&3)  so attn's
//        pi-ordered V A-frags are contiguous b128 reads.
// ---------------------------------------------------------------------------
__global__ __launch_bounds__(512, 4) void gemm_qkv(
    const unsigned short* __restrict__ xb, const unsigned short* __restrict__ yb,
    const unsigned short* __restrict__ WqT, const unsigned short* __restrict__ WkT,
    const unsigned short* __restrict__ WvT,
    const float* __restrict__ bq, const float* __restrict__ bk,
    const float* __restrict__ bv,
    unsigned short* __restrict__ Qb, unsigned short* __restrict__ Kb,
    unsigned short* __restrict__ Vtb) {
  const int z = blockIdx.z;
  const unsigned short* A = (z == 0) ? xb : yb;
  const unsigned short* Bt = (z == 0) ? WqT : (z == 1) ? WkT : WvT;
  const float* bias = (z == 0) ? bq : (z == 1) ? bk : bv;
  unsigned short* Cb = (z == 0) ? Qb : Kb;

  gemm_core(A, Bt, Dd, [&](f32x4 (&acc)[4][2], GemmCtx c) {
#pragma unroll
    for (int i = 0; i < 4; ++i)
#pragma unroll
      for (int j = 0; j < 2; ++j) {
        int col = c.n0 + c.wn + j * 16 + c.lr;
        float bcol = bias[col];
        if (z == 2) {
          int brow = c.m0 + c.wm + i * 16 + c.lg * 4;
          int bi = brow >> 10, nloc = brow & 1023;
          int nperm = (nloc & ~31) | (((nloc >> 2) & 3) << 3) |
                      (((nloc >> 4) & 1) << 2);
          ushort4 o4;
          o4.x = f2bf(acc[i][j][0] + bcol);
          o4.y = f2bf(acc[i][j][1] + bcol);
          o4.z = f2bf(acc[i][j][2] + bcol);
          o4.w = f2bf(acc[i][j][3] + bcol);
          *(ushort4*)(Vtb + ((size_t)bi * Dd + col) * Nn + nperm) = o4;
        } else {
          float scl = (z == 0) ? QSCL : 1.0f;
#pragma unroll
          for (int r = 0; r < 4; ++r) {
            int row = c.m0 + c.wm + i * 16 + c.lg * 4 + r;
            Cb[(size_t)row * Dd + col] = f2bf((acc[i][j][r] + bcol) * scl);
          }
        }
      }
  });
}

// ---------------------------------------------------------------------------
// FF GEMM: Cb = bf16( bf2f(Tres) + relu(acc + bias) )
// ---------------------------------------------------------------------------
__global__ __launch_bounds__(512, 4) void gemm_ff(
    const unsigned short* __restrict__ A, const unsigned short* __restrict__ Bt,
    const float* __restrict__ bias, const unsigned short* __restrict__ Tres,
    unsigned short* __restrict__ Cb) {
  gemm_core(A, Bt, Dd, [&](f32x4 (&acc)[4][2], GemmCtx c) {
#pragma unroll
    for (int i = 0; i < 4; ++i)
#pragma unroll
      for (int j = 0; j < 2; ++j) {
        int col = c.n0 + c.wn + j * 16 + c.lr;
        float bcol = bias[col];
#pragma unroll
        for (int r = 0; r < 4; ++r) {
          int row = c.m0 + c.wm + i * 16 + c.lg * 4 + r;
          size_t idx = (size_t)row * Dd + col;
          Cb[idx] = f2bf(bf2f(Tres[idx]) + fmaxf(acc[i][j][r] + bcol, 0.f));
        }
      }
  });
}

// ---------------------------------------------------------------------------
// Flash attention (measured-best R10 config): 1 block = 8 waves = 256 q-rows
// of one (b,h); 32 q-rows/wave; kv tiles of 64.  Swapped QK^T (S^T=mfma(K,Q))
// -> softmax fully per-lane in exp2 domain; P->PV B-frag in-register via
// v_cvt_pk_bf16_f32; V A-frag one conflict-free ds_read_b128 (c(n) permute);
// row-sums via ones-MFMA; XOR-swizzled dbuf K/V LDS, ONE barrier per tile.
// ---------------------------------------------------------------------------
__global__ __launch_bounds__(512) void attn_fwd(
    const unsigned short* __restrict__ Qg, const unsigned short* __restrict__ Kg,
    const unsigned short* __restrict__ Vt, unsigned short* __restrict__ Obf) {
  __shared__ __attribute__((aligned(16))) unsigned short KVs[2][2][64 * 64];
  char* lbase = (char*)KVs;   // [buf]{K(8KB) | V(8KB)}

  const int bid = blockIdx.y * 4 + blockIdx.x;   // grid (4,128) = 512 wgs
  const int swz = (bid & 7) * 64 + (bid >> 3);
  const int q0 = (swz & 3) * 256;
  const int by = swz >> 2;
  const int b = by >> 4, h = by & 15;

  const int t = threadIdx.x, w = t >> 6, l = t & 63;
  const int lr = l & 15, lg = l >> 4;

  bf16x8 aq[2][2];
#pragma unroll
  for (int i = 0; i < 2; ++i) {
    const unsigned short* qp =
        Qg + ((size_t)b * Nn + q0 + w * 32 + i * 16 + lr) * Dd + h * DH + lg * 8;
    aq[i][0] = *(const bf16x8*)qp;
    aq[i][1] = *(const bf16x8*)(qp + 32);
  }

  u32x4 one4 = {0x3F803F80u, 0x3F803F80u, 0x3F803F80u, 0x3F803F80u};
  const bf16x8 vones = __builtin_bit_cast(bf16x8, one4);

  const size_t baseK = (size_t)b * Nn * Dd + h * DH;
  const size_t baseV = ((size_t)b * Dd + h * DH) * Nn;

  const int srow = t >> 3, sch = t & 7;
  const int sby = srow * 128 + ((sch * 16) ^ ((srow & 7) << 4));

  uint4 kA = *(const uint4*)(Kg + baseK + (size_t)srow * Dd + sch * 8);
  uint4 vA = *(const uint4*)(Vt + baseV + (size_t)srow * Nn + sch * 8);

  *(uint4*)(lbase + sby) = kA;
  *(uint4*)(lbase + 8192 + sby) = vA;
  __syncthreads();

  f32x4 oacc[4][2] = {};
  f32x4 lacc[2] = {};

  for (int kv = 0; kv < Nn / 64; ++kv) {
    char* kcur = lbase + (kv & 1) * 16384;
    char* vcur = kcur + 8192;
    const bool more = (kv + 1) < Nn / 64;
    if (more) {
      int kvo = (kv + 1) * 64;
      kA = *(const uint4*)(Kg + baseK + (size_t)(kvo + srow) * Dd + sch * 8);
      vA = *(const uint4*)(Vt + baseV + (size_t)srow * Nn + kvo + sch * 8);
    }

    f32x4 st[2][4];
    __builtin_amdgcn_s_setprio(1);
#pragma unroll
    for (int j = 0; j < 4; ++j) {
      const int kro = (j * 16 + lr) * 128;
      bf16x8 k0 = ld_frag(kcur + kro + (((lg ^ (lr & 7))) << 4));
      bf16x8 k1 = ld_frag(kcur + kro + ((((lg + 4) ^ (lr & 7))) << 4));
#pragma unroll
      for (int i = 0; i < 2; ++i) {
        f32x4 zz = {0.f, 0.f, 0.f, 0.f};
        MFMA16(zz, k0, aq[i][0]);
        MFMA16(zz, k1, aq[i][1]);
        st[i][j] = zz;
      }
    }
    __builtin_amdgcn_s_setprio(0);

#pragma unroll
    for (int i = 0; i < 2; ++i)
#pragma unroll
      for (int j = 0; j < 4; ++j) {
        st[i][j][0] = exp2f(st[i][j][0]);
        st[i][j][1] = exp2f(st[i][j][1]);
        st[i][j][2] = exp2f(st[i][j][2]);
        st[i][j][3] = exp2f(st[i][j][3]);
      }

#pragma unroll
    for (int m = 0; m < 2; ++m) {
      bf16x8 pb[2];
#pragma unroll
      for (int i = 0; i < 2; ++i) {
        u32x4 pk;
        pk[0] = cvt_pk_bf16(st[i][2 * m][0], st[i][2 * m][1]);
        pk[1] = cvt_pk_bf16(st[i][2 * m][2], st[i][2 * m][3]);
        pk[2] = cvt_pk_bf16(st[i][2 * m + 1][0], st[i][2 * m + 1][1]);
        pk[3] = cvt_pk_bf16(st[i][2 * m + 1][2], st[i][2 * m + 1][3]);
        pb[i] = __builtin_bit_cast(bf16x8, pk);
      }
      __builtin_amdgcn_s_setprio(1);
      MFMA16(lacc[0], vones, pb[0]);
      MFMA16(lacc[1], vones, pb[1]);
#pragma unroll
      for (int da = 0; da < 4; ++da) {
        const int vrow = da * 16 + lr;
        bf16x8 va = ld_frag(
            vcur + vrow * 128 + (((lg + 4 * m) ^ (vrow & 7)) << 4));
        MFMA16(oacc[da][0], va, pb[0]);
        MFMA16(oacc[da][1], va, pb[1]);
      }
      __builtin_amdgcn_s_setprio(0);
    }

    if (more) {
      char* knxt = lbase + ((kv + 1) & 1) * 16384;
      *(uint4*)(knxt + sby) = kA;
      *(uint4*)(knxt + 8192 + sby) = vA;
      __syncthreads();
    }
  }

#pragma unroll
  for (int i = 0; i < 2; ++i) {
    float rd = 1.f / lacc[i][0];
    const size_t orow = (size_t)b * Nn + q0 + w * 32 + i * 16 + lr;
#pragma unroll
    for (int da = 0; da < 4; ++da) {
      ushort4 o4;
      o4.x = f2bf(oacc[da][i][0] * rd);
      o4.y = f2bf(oacc[da][i][1] * rd);
      o4.z = f2bf(oacc[da][i][2] * rd);
      o4.w = f2bf(oacc[da][i][3] * rd);
      *(ushort4*)(Obf + orow * Dd + h * DH + da * 16 + lg * 4) = o4;
    }
  }
}

// ---------------------------------------------------------------------------
// LayerNorm over D=1024, one block (256 thr) per row.  Inputs bf16.
//   MODE 0: t = LN(X + Oin) -> bf16 out_bf
//   MODE 1: out_f = LN(X)   -> f32
// ---------------------------------------------------------------------------
template <int MODE>
__global__ __launch_bounds__(256) void ln_k(
    const unsigned short* __restrict__ X, const unsigned short* __restrict__ Oin,
    const float* __restrict__ gamma, const float* __restrict__ beta,
    unsigned short* __restrict__ out_bf, float* __restrict__ out_f) {
  __shared__ float red[8];
  const int row = blockIdx.x, t = threadIdx.x;
  ushort4 xu = ((const ushort4*)(X + (size_t)row * Dd))[t];
  float4 v = {bf2f(xu.x), bf2f(xu.y), bf2f(xu.z), bf2f(xu.w)};
  if (MODE == 0) {
    ushort4 o = ((const ushort4*)(Oin + (size_t)row * Dd))[t];
    v.x += bf2f(o.x); v.y += bf2f(o.y); v.z += bf2f(o.z); v.w += bf2f(o.w);
  }
  float s = v.x + v.y + v.z + v.w;
#pragma unroll
  for (int o = 32; o > 0; o >>= 1) s += __shfl_xor(s, o, 64);
  if ((t & 63) == 0) red[t >> 6] = s;
  __syncthreads();
  float mean = (red[0] + red[1] + red[2] + red[3]) * (1.f / 1024.f);
  float dx = v.x - mean, dy = v.y - mean, dz = v.z - mean, dw = v.w - mean;
  float s2 = dx * dx + dy * dy + dz * dz + dw * dw;
#pragma unroll
  for (int o = 32; o > 0; o >>= 1) s2 += __shfl_xor(s2, o, 64);
  if ((t & 63) == 0) red[4 + (t >> 6)] = s2;
  __syncthreads();
  float var = (red[4] + red[5] + red[6] + red[7]) * (1.f / 1024.f);
  float rstd = rsqrtf(var + 1e-6f);
  float4 g = ((const float4*)gamma)[t];
  float4 bb = ((const float4*)beta)[t];
  float r0 = dx * rstd * g.x + bb.x;
  float r1 = dy * rstd * g.y + bb.y;
  float r2 = dz * rstd * g.z + bb.z;
  float r3 = dw * rstd * g.w + bb.w;
  if (MODE == 0) {
    ushort4 o4;
    o4.x = f2bf(r0); o4.y = f2bf(r1); o4.z = f2bf(r2); o4.w = f2bf(r3);
    ((ushort4*)(out_bf + (size_t)row * Dd))[t] = o4;
  } else {
    float4 o4 = {r0, r1, r2, r3};
    ((float4*)(out_f + (size_t)row * Dd))[t] = o4;
  }
}

// ---------------------------------------------------------------------------
extern "C" void kernel_launch(void* const* d_in, const int* in_sizes, int n_in,
                              void* d_out, int out_size, void* d_ws, size_t ws_size,
                              hipStream_t stream) {
  const float* x  = (const float*)d_in[0];
  const float* y  = (const float*)d_in[1];
  const float* Wq = (const float*)d_in[2];
  const float* bq = (const float*)d_in[3];
  const float* Wk = (const float*)d_in[4];
  const float* bk = (const float*)d_in[5];
  const float* Wv = (const float*)d_in[6];
  const float* bv = (const float*)d_in[7];
  const float* Wf = (const float*)d_in[8];
  const float* bf = (const float*)d_in[9];
  const float* g1 = (const float*)d_in[10];
  const float* b1 = (const float*)d_in[11];
  const float* g2 = (const float*)d_in[12];
  const float* b2 = (const float*)d_in[13];

  char* ws = (char*)d_ws;
  const size_t MB = 1024 * 1024;
  // workspace (88 MB). Lifetime-disjoint aliases: Obf<-yb, tb<-Qb, ub<-Kb.
  unsigned short* xb  = (unsigned short*)(ws + 0 * MB);   // live -> LN1
  unsigned short* yb  = (unsigned short*)(ws + 16 * MB);
  unsigned short* WqT = (unsigned short*)(ws + 32 * MB);
  unsigned short* WkT = (unsigned short*)(ws + 34 * MB);
  unsigned short* WvT = (unsigned short*)(ws + 36 * MB);
  unsigned short* WfT = (unsigned short*)(ws + 38 * MB);
  unsigned short* Qb  = (unsigned short*)(ws + 40 * MB);
  unsigned short* Kb  = (unsigned short*)(ws + 56 * MB);
  unsigned short* Vtb = (unsigned short*)(ws + 72 * MB);  // [B][D][c(N)]
  unsigned short* Obf = (unsigned short*)(ws + 16 * MB);  // alias yb
  unsigned short* tb  = (unsigned short*)(ws + 40 * MB);  // alias Qb
  unsigned short* ub  = (unsigned short*)(ws + 56 * MB);  // alias Kb

  prep<<<dim3(1024, 1, 6), 256, 0, stream>>>(
      x, y, xb, yb, Wq, Wk, Wv, Wf, WqT, WkT, WvT, WfT);

  gemm_qkv<<<dim3(8, 64, 3), 512, 0, stream>>>(
      xb, yb, WqT, WkT, WvT, bq, bk, bv, Qb, Kb, Vtb);

  attn_fwd<<<dim3(4, 128), 512, 0, stream>>>(Qb, Kb, Vtb, Obf);

  ln_k<0><<<Mrows, 256, 0, stream>>>(xb, Obf, g1, b1, tb, nullptr);

  gemm_ff<<<dim3(8, 64), 512, 0, stream>>>(tb, WfT, bf, tb, ub);

  ln_k<1><<<Mrows, 256, 0, stream>>>(ub, nullptr, g2, b2, nullptr, (float*)d_out);
}